// Round 1
// baseline (1082.115 us; speedup 1.0000x reference)
//
#include <hip/hip_runtime.h>
#include <math.h>

#define DIM   128
#define FDIM  2048
#define MSIZE 100000

// 8 bf16 = 4 VGPRs : MFMA A/B operand for 32x32x16_bf16
using bf16x8 = __attribute__((ext_vector_type(8))) __bf16;
// 16 f32 : MFMA C/D operand for 32x32
using f32x16 = __attribute__((ext_vector_type(16))) float;

// ---------------------------------------------------------------------------
// Kernel 1: repack Lambdas [128][2048] fp32 (row-major, K x N) into bf16
// MFMA B-fragment order in workspace:
//   chunk c = ntile*8 + ks   (ntile in [0,64): 32-col tile; ks in [0,8): k-step)
//   Bw[c*64 + lane] = { Lambdas[ks*16 + (lane>>5)*8 + j][ntile*32 + (lane&31)] : j=0..7 }
// so the GEMM kernel fetches a whole wave's B fragment with one contiguous
// 64-lane x 16 B global_load_dwordx4 (1 KiB, perfectly coalesced, L2-hot).
// ---------------------------------------------------------------------------
__global__ __launch_bounds__(256) void prep_B(const float* __restrict__ L,
                                              bf16x8* __restrict__ Bw) {
  int tid  = blockIdx.x * 256 + threadIdx.x;   // 0 .. 32767 (512 chunks x 64 lanes)
  int lane = tid & 63;
  int c    = tid >> 6;                         // 0..511
  int ntile = c >> 3;
  int ks    = c & 7;
  int n  = ntile * 32 + (lane & 31);
  int k0 = ks * 16 + (lane >> 5) * 8;
  bf16x8 w;
#pragma unroll
  for (int j = 0; j < 8; ++j) w[j] = (__bf16)L[(k0 + j) * FDIM + n];
  Bw[c * 64 + lane] = w;
}

// ---------------------------------------------------------------------------
// Kernel 2: fused renorm(A) -> bf16 -> GEMM (MFMA) -> cos epilogue.
// Block = 256 threads (4 waves), BM = 64 rows, sweeps full N=2048.
// A staged once into LDS (row stride 136 bf16 = 272 B: 16B-aligned, and
// 272/4 mod 32 == 4 -> b128 fragment reads hit the structural-minimum
// bank schedule). No __syncthreads in the N loop (A-LDS is read-only).
// ---------------------------------------------------------------------------
__global__ __launch_bounds__(256, 4) void rff_gemm(
    const float* __restrict__ A, const bf16x8* __restrict__ Bw,
    const float* __restrict__ bias, float* __restrict__ out) {
  __shared__ alignas(16) __bf16 Alds[64 * 136];

  const int tid    = threadIdx.x;
  const int lane   = tid & 63;
  const int wave   = tid >> 6;      // 0..3
  const int rowblk = blockIdx.x * 64;

  // ---- stage A: Poincare renorm + bf16 convert, 4 threads per row ----
  {
    int row  = tid >> 2;            // 0..63
    int part = tid & 3;             // 32 cols each
    int grow = rowblk + row;
    float v[32];
    float ss = 0.f;
    if (grow < MSIZE) {
      const float4* p = (const float4*)(A + (size_t)grow * DIM + part * 32);
#pragma unroll
      for (int i = 0; i < 8; ++i) {
        float4 q = p[i];
        v[i * 4 + 0] = q.x; v[i * 4 + 1] = q.y;
        v[i * 4 + 2] = q.z; v[i * 4 + 3] = q.w;
        ss += q.x * q.x + q.y * q.y + q.z * q.z + q.w * q.w;
      }
    } else {
#pragma unroll
      for (int i = 0; i < 32; ++i) v[i] = 0.f;
    }
    // combine partial sum-of-squares across the 4 lanes of this row
    ss += __shfl_xor(ss, 1, 4);
    ss += __shfl_xor(ss, 2, 4);
    float nrm = sqrtf(ss);
    float f   = fminf(1.0f, 0.99999f / fmaxf(nrm, 1e-5f));  // min(1,(1-EPS)/max(n,EPS))
    bf16x8* dst = (bf16x8*)&Alds[row * 136 + part * 32];
#pragma unroll
    for (int i = 0; i < 4; ++i) {
      bf16x8 w;
#pragma unroll
      for (int j = 0; j < 8; ++j) w[j] = (__bf16)(v[i * 8 + j] * f);
      dst[i] = w;
    }
  }
  __syncthreads();

  const int nlane = lane & 31;
  const int half  = lane >> 5;
  // A-fragment LDS base: lane l holds A[m = l&31][k = (l>>5)*8 + j]
  const __bf16* a0base = &Alds[(lane & 31) * 136 + half * 8];
  const __bf16* a1base = a0base + 32 * 136;

  const bool do_hi = (rowblk + 32) < MSIZE;   // block-uniform tail predicate

  for (int nt = 0; nt < 16; ++nt) {
    const int ntile = nt * 4 + wave;          // each wave owns a 32-col strip
    const int n0    = ntile * 32;
    const float bv  = bias[n0 + nlane];       // C-layout col = lane&31 (L1-hot)

    f32x16 acc0, acc1;
#pragma unroll
    for (int i = 0; i < 16; ++i) { acc0[i] = 0.f; acc1[i] = 0.f; }

    const bf16x8* bptr = Bw + ntile * 8 * 64 + lane;
#pragma unroll
    for (int ks = 0; ks < 8; ++ks) {
      bf16x8 bf  = bptr[ks * 64];                          // global dwordx4, coalesced
      bf16x8 af0 = *(const bf16x8*)(a0base + ks * 16);     // ds_read_b128
      bf16x8 af1 = *(const bf16x8*)(a1base + ks * 16);     // ds_read_b128
      acc0 = __builtin_amdgcn_mfma_f32_32x32x16_bf16(af0, bf, acc0, 0, 0, 0);
      acc1 = __builtin_amdgcn_mfma_f32_32x32x16_bf16(af1, bf, acc1, 0, 0, 0);
    }

    // epilogue: 0.125 * cos(acc + bias). v_cos_f32 takes revolutions; fract first.
    float* outcol = out + n0 + nlane;
#pragma unroll
    for (int reg = 0; reg < 16; ++reg) {
      int r  = (reg & 3) + 8 * (reg >> 2) + 4 * half;      // C/D row map (32x32)
      int g0 = rowblk + r;
      float t0 = 0.125f * __builtin_amdgcn_cosf(
                   __builtin_amdgcn_fractf((acc0[reg] + bv) * 0.15915494f));
      outcol[(size_t)g0 * FDIM] = t0;                      // 128 B full-line store
      if (do_hi) {
        float t1 = 0.125f * __builtin_amdgcn_cosf(
                     __builtin_amdgcn_fractf((acc1[reg] + bv) * 0.15915494f));
        outcol[(size_t)(g0 + 32) * FDIM] = t1;
      }
    }
  }
}

// ---------------------------------------------------------------------------
extern "C" void kernel_launch(void* const* d_in, const int* in_sizes, int n_in,
                              void* d_out, int out_size, void* d_ws, size_t ws_size,
                              hipStream_t stream) {
  const float* A    = (const float*)d_in[0];   // lt_weight [100000,128] fp32
  const float* L    = (const float*)d_in[1];   // Lambdas   [128,2048]  fp32
  const float* bias = (const float*)d_in[2];   // bias      [2048]      fp32
  float* out = (float*)d_out;                  // [100000,2048] fp32
  bf16x8* Bw = (bf16x8*)d_ws;                  // 512 KiB repacked B

  prep_B<<<128, 256, 0, stream>>>(L, Bw);
  const int grid = (MSIZE + 63) / 64;          // 1563
  rff_gemm<<<grid, 256, 0, stream>>>(A, Bw, bias, out);
}